// Round 12
// baseline (128.665 us; speedup 1.0000x reference)
//
#include <hip/hip_runtime.h>
#include <cmath>

// Conductance-based LIF scan: T=512 steps, N=65536 neurons.
// R11: WAVE-DOUBLING at constant memory traffic. Evidence: effective BW is
// monotone in resident wave count (512w: 4.06 TB/s; 1024w: 5.35; copy@full
// occupancy: 6.29) and insensitive to width/depth/VALU. So: 2048 waves
// (8/CU), each owning 32 neurons; lanes 32-63 duplicate lanes 0-31's
// computation bit-exactly (li = lane&31) and are used to MERGE memory ops:
//   - 1 global_load_lds: ge (lanes 0-31) + gi (lanes 32-63), one step
//   - 1 global_load_lds: z for steps t (lo) and t+1 (hi)
//   - 1 NT store: mem (lanes 0-31) + spk (lanes 32-63)
// => 6 loads + 4 stores per wave per 4-step group; per-CU instruction and
// byte profile IDENTICAL to R9, wave count 2x. Zero barriers; store-order-
// robust counted vmcnt (R9 rule, loads-only count): steady K = 3*6 = 18.
//
// Numerics identical to R5/R7/R9 (passed, absmax 0.00390625):
// FMA-contracted, rcp-div, __expf. gA == 0 (ADAPT_INC==0), elided.

__device__ __forceinline__ void gload_lds4(const float* g, float* l) {
    __builtin_amdgcn_global_load_lds(
        (const __attribute__((address_space(1))) unsigned int*)(const void*)g,
        (__attribute__((address_space(3))) unsigned int*)(void*)l,
        4, 0, 0);
}

#define WAITV(n) asm volatile("s_waitcnt vmcnt(" #n ")" ::: "memory")

__global__ __launch_bounds__(256, 2) void lif_scan(
    const float* __restrict__ g_exc,
    const float* __restrict__ g_inh,
    const float* __restrict__ noise,
    const float* __restrict__ v_th,
    const float* __restrict__ tau_ref,
    float* __restrict__ out_spk,   // d_out[0 .. T*N)
    float* __restrict__ out_mem,   // d_out[T*N .. 2*T*N)
    int N, int T,
    float cGE, float cGI, float cALPHA, float cSIGMA)
{
    // ring: 16 slots = 4 batches of 4 steps
    __shared__ float gegi[16][4][64];   // [slot][wave][ge:0-31 | gi:32-63] 16 KiB
    __shared__ float zs[8][4][64];      // [slot/2][wave][z(t):0-31 | z(t+1):32-63] 8 KiB

    const int tid  = threadIdx.x;
    const int lane = tid & 63;
    const int wid  = tid >> 6;
    const int li   = lane & 31;
    const bool hi  = (lane & 32) != 0;

    const int W  = blockIdx.x * 4 + wid;       // global wave id, 0..2047
    const int nb = W * 32 + li;                // neuron (duplicated across halves)

    // per-lane merged source/dest bases
    const float* __restrict__ baseAB = (hi ? g_inh : g_exc) + nb;  // ge | gi
    const float* __restrict__ baseZ  = noise + nb + (hi ? N : 0);  // z(t) | z(t+1)
    float* __restrict__ baseOut      = (hi ? out_spk : out_mem) + nb; // mem | spk

    const float vth = v_th[nb];
    const float trf = tau_ref[nb];

    float v = 0.f, gE = 0.f, gI = 0.f, ref = 0.f, ou = 0.f;

    // stage steps tb..tb+3 into ring slots sb..sb+3: 4 merged ge/gi loads
    // + 2 merged z loads = 6 instrs (256B each)
    auto issueB = [&](int tb, int sb) {
        #pragma unroll
        for (int k = 0; k < 4; ++k)
            gload_lds4(baseAB + (size_t)(tb + k) * (size_t)N, &gegi[sb + k][wid][0]);
        #pragma unroll
        for (int j = 0; j < 2; ++j)
            gload_lds4(baseZ + (size_t)(tb + 2 * j) * (size_t)N, &zs[(sb >> 1) + j][wid][0]);
    };

    auto step = [&](float ge_in, float gi_in, float z, int tt) {
        gE = __builtin_fmaf(gE, cGE, ge_in);
        gI = __builtin_fmaf(gI, cGI, gi_in);

        const float gt  = 1.0f + gE + gI;
        const float num = __builtin_fmaf(gI, -0.5f, gE * 3.0f);
        const float vinf = num * __builtin_amdgcn_rcpf(gt);

        const float decay = __expf(-0.05f * gt);

        v = __builtin_fmaf(v - vinf, decay, vinf);

        ou = __builtin_fmaf(ou, cALPHA, cSIGMA * z);
        v = v + ou;

        const bool in_ref = (ref > 0.0f);
        const bool spike  = (v >= vth) && (!in_ref);
        v = (in_ref || spike) ? 0.0f : v;
        ref = spike ? trf : fmaxf(ref - 1.0f, 0.0f);

        // merged output: lanes 0-31 store v (mem), lanes 32-63 store spike
        const float outval = hi ? (spike ? 1.0f : 0.0f) : v;
        __builtin_nontemporal_store(outval, baseOut + (size_t)tt * (size_t)N);
    };

    // one 4-step group: read slots sb..sb+3, refill them for t0+16,
    // compute 4 steps (+4 merged NT stores)
    auto group = [&](int t0, int sb, bool issue) {
        float ge4[4], gi4[4], z4[4];
        #pragma unroll
        for (int k = 0; k < 4; ++k) {
            const int s = sb + k;
            ge4[k] = gegi[s][wid][li];
            gi4[k] = gegi[s][wid][32 + li];
            z4[k]  = zs[s >> 1][wid][((s & 1) << 5) + li];
        }
        // slot data in VGPRs before its refill is issued
        asm volatile("s_waitcnt lgkmcnt(0)" ::: "memory");
        if (issue) issueB(t0 + 16, sb);
        #pragma unroll
        for (int k = 0; k < 4; ++k)
            step(ge4[k], gi4[k], z4[k], t0 + k);
    };

    // prologue: 4 batches in flight (slots 0-3, 4-7, 8-11, 12-15)
    issueB(0, 0);
    issueB(4, 4);
    issueB(8, 8);
    issueB(12, 12);

    // steady: K = 3 in-flight refill batches x 6 loads = 18 (loads-only
    // robust count; no assumption on store retirement order)
    for (int p = 0; p <= 30; ++p) {
        WAITV(18); group(16 * p,      0,  true);
        WAITV(18); group(16 * p + 4,  4,  true);
        WAITV(18); group(16 * p + 8,  8,  true);
        WAITV(18); group(16 * p + 12, 12, true);
    }
    // epilogue groups (no refill): newer loads = 18, 12, 6, 0
    WAITV(18); group(496, 0,  false);
    WAITV(12); group(500, 4,  false);
    WAITV(6);  group(504, 8,  false);
    WAITV(0);  group(508, 12, false);
}

extern "C" void kernel_launch(void* const* d_in, const int* in_sizes, int n_in,
                              void* d_out, int out_size, void* d_ws, size_t ws_size,
                              hipStream_t stream) {
    const float* g_exc   = (const float*)d_in[0];
    const float* g_inh   = (const float*)d_in[1];
    const float* noise   = (const float*)d_in[2];
    const float* v_th    = (const float*)d_in[3];
    const float* tau_ref = (const float*)d_in[4];

    const int N = in_sizes[3];            // 65536
    const int T = in_sizes[0] / N;        // 512

    float* out_spk = (float*)d_out;
    float* out_mem = (float*)d_out + (size_t)T * (size_t)N;

    // Constants computed in double exactly as the Python reference does.
    const double ge_decay = exp(-1.0 / 5.0);
    const double gi_decay = exp(-1.0 / 10.0);
    const double ou_alpha = exp(-1.0 / 5.0);
    const double ou_sigma = 0.02 * sqrt(1.0 - ou_alpha * ou_alpha);

    const int block = 256;                // 4 waves/block, 32 neurons/wave
    const int grid  = N / 128;            // 512 blocks -> 2/CU, 8 waves/CU
    lif_scan<<<grid, block, 0, stream>>>(
        g_exc, g_inh, noise, v_th, tau_ref, out_spk, out_mem,
        N, T,
        (float)ge_decay, (float)gi_decay, (float)ou_alpha, (float)ou_sigma);
}